// Round 2
// baseline (112.502 us; speedup 1.0000x reference)
//
#include <hip/hip_runtime.h>
#include <math.h>

#define H_ 1024
#define W_ 2048
#define HW_ (H_ * W_)
#define NB_ 2048                           // half-row per block
#define TPB_ 256                           // 4 px/thread
#define HALF_ 1024

#define FLUXF     0.87890625f              // 300*(6/2048)
#define F_FACT    0.002574920654296875f    // 300*(6/2048)^2
#define WC0VF     65.96910698f             // 651.83*202.412*0.001/2
#define POROUS_K  0.521986224f             // C1*C2*C4*CT

// Native Clang vector types — required by __builtin_nontemporal_load/store
// (HIP_vector_type float4/int4 are classes and are rejected).
typedef float f32x4 __attribute__((ext_vector_type(4)));
typedef int   i32x4 __attribute__((ext_vector_type(4)));

// b after the sequential .at[].set() chain (later writes win):
//   b[0,:]=3, b[-1,:]=3 ; b[:,-1]=3 ; b[:,1]=0 ; b[1,1:]=0, b[-2,1:]=0 (j>=1!)
__device__ __forceinline__ int fix_b(int raw, int i, int j) {
    if (i == 0 || i == H_ - 1) return 3;
    if (j == W_ - 1) return 3;
    if (j == 1) return 0;
    if ((i == 1 || i == H_ - 2) && j >= 1) return 0;
    return raw;
}

// Half-row per block, 4 px/thread, 256 threads -> 8 blocks/CU (max thread occ).
// Moments (quadratic-in-porous split):
//  s0=sum(wc_bc) s1=sum(a^2) s2=sum(a*c) s3=sum(c^2)
//  s4=sum(aw^2)  s5=sum(aw*q) s6=sum(q^2);  e=a+p*c, w=aw-p*q.
__global__ __launch_bounds__(TPB_, 8)
void k_main(const int* __restrict__ layout, const float* __restrict__ heat_ini,
            const float* __restrict__ wc, const float* __restrict__ heat,
            const float* __restrict__ flow, float* __restrict__ out_hb,
            float* __restrict__ out_eq, float* __restrict__ ws) {
    // XCD-strip swizzle: XCD x owns rows [x*128, (x+1)*128) -> up/down row
    // re-reads hit that XCD's own L2 instead of bouncing to L3.
    const int virt = ((blockIdx.x & 7) << 8) | (blockIdx.x >> 3);
    const int i    = virt >> 1;
    const int jb0  = (virt & 1) * HALF_;
    const int tid  = threadIdx.x;
    const int lj   = tid << 2;
    const int jb   = jb0 + lj;
    const int im = (i == 0) ? 1 : i - 1;
    const int ip = (i == H_ - 1) ? H_ - 2 : i + 1;
    const int* L1 = layout + HW_;
    const int base  = i * W_ + jb;
    const int baseu = im * W_ + jb;
    const int based = ip * W_ + jb;

    // Reused-across-blocks rows (heat, layout ch1): normal (L2-cached) loads.
    i32x4 bc = *(const i32x4*)(L1 + base);
    i32x4 bu = *(const i32x4*)(L1 + baseu);
    i32x4 bd = *(const i32x4*)(L1 + based);
    f32x4 hc = *(const f32x4*)(heat + base);
    f32x4 hu = *(const f32x4*)(heat + baseu);
    f32x4 hd = *(const f32x4*)(heat + based);
    // Single-use streams: nontemporal, keep them out of L2.
    i32x4 g  = __builtin_nontemporal_load((const i32x4*)(layout + base));
    f32x4 hi = __builtin_nontemporal_load((const f32x4*)(heat_ini + base));
    f32x4 w  = __builtin_nontemporal_load((const f32x4*)(wc + base));
    f32x4 u  = __builtin_nontemporal_load((const f32x4*)(flow + base));
    f32x4 v  = __builtin_nontemporal_load((const f32x4*)(flow + HW_ + base));

    // Block-edge halo (masked heat_bc just outside this half-row)
    __shared__ float shb[HALF_ + 2];       // shb[x+1] = masked local x
    if (tid == 0) {
        float hv = 0.0f;
        if (jb0 != 0) {
            int j = jb0 - 1;
            hv = (fix_b(L1[i * W_ + j], i, j) != 1) ? heat[i * W_ + j] : 0.0f;
        }
        shb[0] = hv;
    }
    if (tid == TPB_ - 1) {
        float hv = 0.0f;
        if (jb0 + HALF_ < W_) {
            int j = jb0 + HALF_;
            hv = (fix_b(L1[i * W_ + j], i, j) != 1) ? heat[i * W_ + j] : 0.0f;
        }
        shb[HALF_ + 1] = hv;
    }

    int   bcs[4] = {bc.x, bc.y, bc.z, bc.w};
    int   bus[4] = {bu.x, bu.y, bu.z, bu.w};
    int   bds[4] = {bd.x, bd.y, bd.z, bd.w};
    int   gs[4]  = {g.x, g.y, g.z, g.w};
    float hcs[4] = {hc.x, hc.y, hc.z, hc.w};
    float hus[4] = {hu.x, hu.y, hu.z, hu.w};
    float hds[4] = {hd.x, hd.y, hd.z, hd.w};
    float his[4] = {hi.x, hi.y, hi.z, hi.w};
    float wss[4] = {w.x, w.y, w.z, w.w};
    float us[4]  = {u.x, u.y, u.z, u.w};
    float vs[4]  = {v.x, v.y, v.z, v.w};

    int   bfix[4];
    float hb4[4], oeqs[4];
    #pragma unroll
    for (int k = 0; k < 4; k++) {
        int b = fix_b(bcs[k], i, jb + k);
        bfix[k] = b;
        hb4[k]  = (b != 1) ? hcs[k] : 0.0f;
        oeqs[k] = (b == 1) ? 0.0f : (float)b;
    }
    f32x4 hbv; hbv.x = hb4[0]; hbv.y = hb4[1]; hbv.z = hb4[2]; hbv.w = hb4[3];
    f32x4 oev; oev.x = oeqs[0]; oev.y = oeqs[1]; oev.z = oeqs[2]; oev.w = oeqs[3];
    *(f32x4*)(shb + 1 + lj) = hbv;
    __builtin_nontemporal_store(hbv, (f32x4*)(out_hb + base));
    __builtin_nontemporal_store(oev, (f32x4*)(out_eq + base));
    __syncthreads();

    float acc[7] = {0.f,0.f,0.f,0.f,0.f,0.f,0.f};
    #pragma unroll
    for (int k = 0; k < 4; k++) {
        int j = jb + k;
        int b = bfix[k];
        float hl = (k == 0) ? shb[lj]     : hb4[k - 1];
        float hr = (k == 3) ? shb[lj + 5] : hb4[k + 1];
        float dx = (j == 0 || j == W_ - 1) ? 0.0f : 0.5f * (hr - hl);
        float hbu = (fix_b(bus[k], im, j) != 1) ? hus[k] : 0.0f;
        float hbd = (fix_b(bds[k], ip, j) != 1) ? hds[k] : 0.0f;
        float dy = 0.5f * (hbd - hbu);                  // auto-0 at i=0/H-1

        float ad = his[k] - 0.001f * (us[k] * dx + vs[k] * dy);

        float t  = hb4[k] + 273.15f;
        float t2 = t * t, t3 = t2 * t;
        float cp_a = (28.11f + 0.001967f * t + 4.802e-6f * t2 - 1.966e-9f * t3)
                     * (1000.0f / 28.97f);
        float cp_v = (32.24f + 0.001923f * t + 1.055e-5f * t2 - 3.595e-9f * t3)
                     * (1000.0f / 18.015f);
        float P_v = expf(23.2f - 3816.4f / (t - 46.1f));
        float x_v = 0.62198f * P_v / (101325.0f - P_v);
        float q = 300.0f / (cp_a + cp_v * 0.00725f) * (x_v - 0.00725f);

        float f = (i == 0 || i == H_ - 1) ? 0.0f
                  : fabsf((float)gs[k] - 1.0f) * F_FACT;

        float a_e, c_e;
        if (b == 1) {
            a_e = -f; c_e = 0.0f;
        } else {
            float cx = (b == 4 || b == 9 || b == 10) ? 1.0f
                     : ((b == 6 || b == 8 || b == 11) ? -1.0f : 0.0f);
            float cy = (b == 7 || b == 8 || b == 9) ? 1.0f
                     : ((b == 5 || b == 10 || b == 11) ? -1.0f : 0.0f);
            float extra0 = (b >= 4) ? (FLUXF * (cx * dx + cy * dy) + WC0VF) : 0.0f;
            a_e = ad + extra0 - f;
            c_e = (b >= 4) ? (-0.001f * q) : 0.0f;
        }
        acc[1] += a_e * a_e;
        acc[2] += a_e * c_e;
        acc[3] += c_e * c_e;

        float wm  = (b > 3) ? 1.0f : 0.0f;
        float wcb = wm * wss[k];
        float aw  = WC0VF * wm - wcb;
        acc[0] += wcb;
        acc[4] += aw * aw;
        acc[5] += aw * q;
        acc[6] += q * q;
    }

    #pragma unroll
    for (int off = 32; off > 0; off >>= 1) {
        #pragma unroll
        for (int s = 0; s < 7; s++) acc[s] += __shfl_down(acc[s], off, 64);
    }
    __shared__ float red[TPB_ / 64][7];
    int lane = threadIdx.x & 63, wid = threadIdx.x >> 6;
    if (lane == 0) {
        #pragma unroll
        for (int s = 0; s < 7; s++) red[wid][s] = acc[s];
    }
    __syncthreads();
    if (threadIdx.x == 0) {
        #pragma unroll
        for (int s = 0; s < 7; s++)
            ws[s * NB_ + blockIdx.x] = red[0][s] + red[1][s] + red[2][s] + red[3][s];
    }
}

// Reduce NB_ partials per moment (2x float4 per thread), finish quadratics.
__global__ __launch_bounds__(256)
void k_final(const float* __restrict__ ws, float* __restrict__ out) {
    __shared__ float sred[7][4];
    int tid = threadIdx.x;
    #pragma unroll
    for (int s = 0; s < 7; s++) {
        f32x4 x = *(const f32x4*)(ws + s * NB_ + (tid << 3));
        f32x4 y = *(const f32x4*)(ws + s * NB_ + (tid << 3) + 4);
        float a = (x.x + x.y + x.z + x.w) + (y.x + y.y + y.z + y.w);
        #pragma unroll
        for (int off = 32; off > 0; off >>= 1) a += __shfl_down(a, off, 64);
        if ((tid & 63) == 0) sred[s][tid >> 6] = a;
    }
    __syncthreads();
    if (tid == 0) {
        float S[7];
        #pragma unroll
        for (int s = 0; s < 7; s++)
            S[s] = sred[s][0] + sred[s][1] + sred[s][2] + sred[s][3];
        float mean_wc = S[0] * (1.0f / (float)HW_);
        float p = POROUS_K * sqrtf(mean_wc / WC0VF);
        float energy = S[1] + 2.0f * p * S[2] + p * p * S[3];
        float wcl    = S[4] - 2.0f * p * S[5] + p * p * S[6];
        out[0] = (energy + wcl) * (1.0f / (float)HW_);
    }
}

extern "C" void kernel_launch(void* const* d_in, const int* in_sizes, int n_in,
                              void* d_out, int out_size, void* d_ws, size_t ws_size,
                              hipStream_t stream) {
    const int*   layout   = (const int*)d_in[0];
    const float* heat_ini = (const float*)d_in[1];
    const float* wc       = (const float*)d_in[2];
    const float* heat     = (const float*)d_in[3];
    const float* flow     = (const float*)d_in[4];
    float* out = (float*)d_out;    // [loss(1), heat_bc(HW), eq_mask(HW)]
    float* ws  = (float*)d_ws;     // 7 * NB_ block partials (SoA)

    float* out_hb = out + 1;
    float* out_eq = out + 1 + HW_;

    k_main<<<NB_, TPB_, 0, stream>>>(layout, heat_ini, wc, heat, flow,
                                     out_hb, out_eq, ws);
    k_final<<<1, 256, 0, stream>>>(ws, out);
}